// Round 21
// baseline (94.474 us; speedup 1.0000x reference)
//
#include <hip/hip_runtime.h>
#include <math.h>

#define B_ 8
#define N_ 128
#define L_ 30
#define D_ 256
#define NEGV -1000000000.0f
#define SCALE 0.0625f   // 1/sqrt(256)

// ---- K0 (R15-20-proven): 240 blocks, block l: k[l]=f_w[l]@Wk^T+bk ; k2f[l]=k[l]@Wq ; sv[l]=bq.k[l] ----
__global__ __launch_bounds__(256) void kk2(const float* __restrict__ f_w,
    const float* __restrict__ Wk, const float* __restrict__ bk,
    const float* __restrict__ Wq, const float* __restrict__ bq,
    float* __restrict__ k2f, float* __restrict__ sv) {
  int l = blockIdx.x;              // 240
  int t = threadIdx.x, wave = t >> 6, lane = t & 63;
  __shared__ float part[4][16][65];
  __shared__ float kl[D_];
  __shared__ float wsum[4];

  float4 x4 = ((const float4*)(f_w + (size_t)l * D_))[lane];

  for (int g = 0; g < 4; ++g) {
    int dbase = wave * 64 + g * 16;
#pragma unroll
    for (int i = 0; i < 16; ++i) {
      float4 w4 = ((const float4*)(Wk + (size_t)(dbase + i) * D_))[lane];
      part[wave][i][lane] = w4.x*x4.x + w4.y*x4.y + w4.z*x4.z + w4.w*x4.w;
    }
    float s = 0.f;
#pragma unroll
    for (int j = 0; j < 16; ++j)
      s += part[wave][lane & 15][(lane >> 4) * 16 + j];
    s += __shfl_xor(s, 16);
    s += __shfl_xor(s, 32);
    if (lane < 16) kl[dbase + lane] = s + bk[dbase + lane];
  }
  __syncthreads();

  float a0 = 0.f, a1 = 0.f, a2 = 0.f, a3 = 0.f;
#pragma unroll 4
  for (int d4 = 0; d4 < 64; ++d4) {
    float4 kv = ((const float4*)kl)[d4];
    a0 += kv.x * Wq[(size_t)(4*d4+0) * D_ + t];
    a1 += kv.y * Wq[(size_t)(4*d4+1) * D_ + t];
    a2 += kv.z * Wq[(size_t)(4*d4+2) * D_ + t];
    a3 += kv.w * Wq[(size_t)(4*d4+3) * D_ + t];
  }
  k2f[(size_t)l * D_ + t] = (a0 + a1) + (a2 + a3);

  float p = bq[t] * kl[t];
#pragma unroll
  for (int off = 32; off >= 1; off >>= 1) p += __shfl_xor(p, off);
  if (lane == 0) wsum[wave] = p;
  __syncthreads();
  if (t == 0) sv[l] = wsum[0] + wsum[1] + wsum[2] + wsum[3];
}

// ---- K1 (R14-20-proven): 256 blocks x 4 n-rows: aw=(f_b.k2f+sv)*scale -> softmax -> f_bq ----
__global__ __launch_bounds__(256) void aw_fbq(const float* __restrict__ f_b,
    const float* __restrict__ f_w, const float* __restrict__ f_s,
    const float* __restrict__ qmask, const float* __restrict__ lmask,
    const float* __restrict__ k2f, const float* __restrict__ sv,
    float* __restrict__ fbq) {
  int blk = blockIdx.x;
  int b = blk >> 5, n0 = (blk & 31) * 4;
  int t = threadIdx.x;

  __shared__ float k2l[L_][260];
  __shared__ float fbl[4][260];
  __shared__ float pdot[120][2];
  __shared__ float awl[4][32];
  __shared__ float slds[32];

  for (int r = 0; r < 4; ++r)
    fbl[r][t] = f_b[(size_t)(b * N_ + n0 + r) * D_ + t];
  for (int l = 0; l < L_; ++l)
    k2l[l][t] = k2f[(size_t)(b * L_ + l) * D_ + t];
  if (t < L_) slds[t] = sv[b * L_ + t];
  __syncthreads();

  if (t < 240) {
    int p = t % 120, half = t / 120;
    int r = p / 30, l = p % 30;
    const float4* fr = (const float4*)(fbl[r] + half * 128);
    const float4* kr = (const float4*)(k2l[l] + half * 128);
    float ac[4] = {0.f, 0.f, 0.f, 0.f};
#pragma unroll
    for (int j = 0; j < 32; ++j) {
      float4 fv = fr[j], kv = kr[j];
      ac[j & 3] += fv.x*kv.x + fv.y*kv.y + fv.z*kv.z + fv.w*kv.w;
    }
    pdot[p][half] = (ac[0] + ac[1]) + (ac[2] + ac[3]);
  }
  __syncthreads();

  if (t < 120) {
    int r = t / 30, l = t % 30;
    float acc = pdot[t][0] + pdot[t][1];
    float aw = (acc + slds[l]) * SCALE;
    float qm = qmask[b * L_ + l];
    awl[r][l] = (qm == 0.f) ? NEGV : aw * qm;
  }
  __syncthreads();

  if (t < 4) {
    float mx = -1e30f;
    for (int l = 0; l < L_; ++l) mx = fmaxf(mx, awl[t][l]);
    float s = 0.f;
    for (int l = 0; l < L_; ++l) { float e = __expf(awl[t][l] - mx); awl[t][l] = e; s += e; }
    float inv = 1.f / s;
    for (int l = 0; l < L_; ++l) awl[t][l] *= inv;
  }
  __syncthreads();

  for (int l = 0; l < L_; ++l)
    k2l[l][t] = f_w[(size_t)(b * L_ + l) * D_ + t];
  __syncthreads();

  float fsd = f_s[b * D_ + t];
  for (int r = 0; r < 4; ++r) {
    float f0 = 0.f, f1 = 0.f;
#pragma unroll
    for (int l = 0; l < L_; l += 2) {
      f0 += awl[r][l] * k2l[l][t];
      f1 += awl[r][l + 1] * k2l[l + 1][t];
    }
    float lm = lmask[b * N_ + n0 + r];
    fbq[(size_t)(b * N_ + n0 + r) * D_ + t] = fbl[r][t] * ((f0 + f1) * lm + fsd);
  }
}

// ---- K2 (R20-proven, byte-identical): fbq-first -> deep f_m preload -> softmax -> fbb -> stream ----
__global__ __launch_bounds__(256) void fused_stream(const float* __restrict__ f_b,
    const float* __restrict__ f_m, const float* __restrict__ f_s,
    const float* __restrict__ lmask, const float* __restrict__ fbq,
    float* __restrict__ out) {
  int bn = blockIdx.x, b = bn >> 7, n = bn & 127;
  int t = threadIdx.x, w = t >> 6, lane = t & 63;

  __shared__ float part[4][32][65];   // 33.3 KB
  __shared__ float a_lds[N_];
  __shared__ float sm[8];
  __shared__ float4 red[3][64];       // 3 KB
  __shared__ float fbbred[D_];        // 1 KB

  const float4* fmb = (const float4*)(f_m + (size_t)bn * N_ * D_);
  const float4* fbb = (const float4*)(f_b + (size_t)b * N_ * D_);
  int m0 = w * 32;

  float4 qv = ((const float4*)(fbq + (size_t)bn * D_))[lane];
#pragma unroll 8
  for (int i = 0; i < 32; ++i) {
    float4 v = ((const float4*)(fbq + (size_t)(b * N_ + m0 + i) * D_))[lane];
    part[w][i][lane] = v.x*qv.x + v.y*qv.y + v.z*qv.z + v.w*qv.w;
  }
  __builtin_amdgcn_sched_barrier(0);

  float4 pA[8], pB[8];
#pragma unroll
  for (int i = 0; i < 8; ++i) pA[i] = fmb[(size_t)(m0 + i) * 64 + lane];
#pragma unroll
  for (int i = 0; i < 8; ++i) pB[i] = fmb[(size_t)(m0 + 8 + i) * 64 + lane];
  __builtin_amdgcn_sched_barrier(0);

  __syncthreads();
  float s = 0.f;
#pragma unroll
  for (int j = 0; j < 32; ++j)
    s += part[w][lane & 31][(lane >> 5) * 32 + j];
  s += __shfl_xor(s, 32);
  if (lane < 32) a_lds[m0 + (lane & 31)] = s;
  __syncthreads();

  float lmn = lmask[b * N_ + n];
  float e = 0.f;
  if (t < N_) {
    float lm = lmask[b * N_ + t];
    float v = (lm == 0.f) ? NEGV : a_lds[t] * SCALE * lm;
    float mx = v;
#pragma unroll
    for (int off = 32; off >= 1; off >>= 1) mx = fmaxf(mx, __shfl_xor(mx, off));
    if (lane == 0) sm[w] = mx;
  }
  __syncthreads();
  if (t < N_) {
    float lm = lmask[b * N_ + t];
    float v = (lm == 0.f) ? NEGV : a_lds[t] * SCALE * lm;
    float gmax = fmaxf(sm[0], sm[1]);
    e = __expf(v - gmax);
    float ss = e;
#pragma unroll
    for (int off = 32; off >= 1; off >>= 1) ss += __shfl_xor(ss, off);
    if (lane == 0) sm[4 + w] = ss;
  }
  __syncthreads();
  if (t < N_) {
    float tot = sm[4] + sm[5];
    a_lds[t] = e * (lmn / tot);
  }
  __syncthreads();

  {
    const float* fbcol = f_b + (size_t)b * N_ * D_ + t;
    float f0 = 0.f, f1 = 0.f;
#pragma unroll 8
    for (int m = 0; m < N_; m += 2) {
      f0 += a_lds[m]     * fbcol[(size_t)m * D_];
      f1 += a_lds[m + 1] * fbcol[(size_t)(m + 1) * D_];
    }
    fbbred[t] = f0 + f1;
  }

  float4 fs4 = ((const float4*)(f_s + (size_t)b * D_))[lane];
  const float CLOG = -1.44269504088896f;  // -log2(e)
  float4 cs;
  cs.x = fs4.x * CLOG; cs.y = fs4.y * CLOG;
  cs.z = fs4.z * CLOG; cs.w = fs4.w * CLOG;
  float4 acc = make_float4(0.f, 0.f, 0.f, 0.f);

  auto compute8 = [&](float4 (&P)[8], int mbase) {
#pragma unroll
    for (int i = 0; i < 8; ++i) {
      float a = a_lds[mbase + i];
      float4 fm4 = P[i];
      float gx = __builtin_amdgcn_rcpf(1.f + __builtin_amdgcn_exp2f(fm4.x * cs.x));
      float gy = __builtin_amdgcn_rcpf(1.f + __builtin_amdgcn_exp2f(fm4.y * cs.y));
      float gz = __builtin_amdgcn_rcpf(1.f + __builtin_amdgcn_exp2f(fm4.z * cs.z));
      float gw = __builtin_amdgcn_rcpf(1.f + __builtin_amdgcn_exp2f(fm4.w * cs.w));
      acc.x += a * (gx * fm4.x);
      acc.y += a * (gy * fm4.y);
      acc.z += a * (gz * fm4.z);
      acc.w += a * (gw * fm4.w);
    }
  };

  compute8(pA, m0);
#pragma unroll
  for (int i = 0; i < 8; ++i) pA[i] = fmb[(size_t)(m0 + 16 + i) * 64 + lane];
  compute8(pB, m0 + 8);
#pragma unroll
  for (int i = 0; i < 8; ++i) pB[i] = fmb[(size_t)(m0 + 24 + i) * 64 + lane];
  compute8(pA, m0 + 16);
  compute8(pB, m0 + 24);

  if (w > 0) red[w - 1][lane] = acc;
  __syncthreads();
  if (w == 0) {
#pragma unroll
    for (int j = 0; j < 3; ++j) {
      float4 r4 = red[j][lane];
      acc.x += r4.x; acc.y += r4.y; acc.z += r4.z; acc.w += r4.w;
    }
    float4 fbn = fbb[(size_t)n * 64 + lane];
    float4 bb = ((const float4*)fbbred)[lane];
    float4 o;
    o.x = fbn.x + acc.x + lmn * bb.x;
    o.y = fbn.y + acc.y + lmn * bb.y;
    o.z = fbn.z + acc.z + lmn * bb.z;
    o.w = fbn.w + acc.w + lmn * bb.w;
    ((float4*)out)[(size_t)bn * 64 + lane] = o;
  }
}

extern "C" void kernel_launch(void* const* d_in, const int* in_sizes, int n_in,
                              void* d_out, int out_size, void* d_ws, size_t ws_size,
                              hipStream_t stream) {
  const float* f_b   = (const float*)d_in[0];
  const float* f_w   = (const float*)d_in[1];
  const float* f_s   = (const float*)d_in[2];
  const float* f_m   = (const float*)d_in[3];
  const float* qmask = (const float*)d_in[4];
  const float* lmask = (const float*)d_in[5];
  const float* Wq    = (const float*)d_in[6];
  const float* bq    = (const float*)d_in[7];
  const float* Wk    = (const float*)d_in[8];
  const float* bk    = (const float*)d_in[9];
  float* out = (float*)d_out;

  float* ws  = (float*)d_ws;
  float* k2f = ws;                          // 61440 (pad 65536)
  float* sv  = ws + 65536;                  // 240  (pad 1024)
  float* fbq = ws + 131072;                 // 262144

  // SLOPE DECOMPOSITION: kk2 x4 and aw_fbq x4 (idempotent re-writes of identical
  // outputs — deterministic, replay-safe). Marginal over R20's 52.7us =
  // 3*(kk2+gap) + 3*(aw_fbq+gap) = 3 * prep-quantum.
  for (int rep = 0; rep < 4; ++rep)
    hipLaunchKernelGGL(kk2, dim3(B_ * L_), dim3(256), 0, stream,
                       f_w, Wk, bk, Wq, bq, k2f, sv);
  for (int rep = 0; rep < 4; ++rep)
    hipLaunchKernelGGL(aw_fbq, dim3(256), dim3(256), 0, stream,
                       f_b, f_w, f_s, qmask, lmask, k2f, sv, fbq);
  hipLaunchKernelGGL(fused_stream, dim3(B_ * N_), dim3(256), 0, stream,
                     f_b, f_m, f_s, lmask, fbq, out);
}

// Round 22
// 56.033 us; speedup vs baseline: 1.6860x; 1.6860x over previous
//
#include <hip/hip_runtime.h>
#include <math.h>

#define B_ 8
#define N_ 128
#define L_ 30
#define D_ 256
#define NEGV -1000000000.0f
#define SCALE 0.0625f   // 1/sqrt(256)

typedef const __attribute__((address_space(1))) void* as1_cvptr;
typedef __attribute__((address_space(3))) void* as3_vptr;

// ---- K0 (R15-20-proven): 240 blocks, block l: k[l]=f_w[l]@Wk^T+bk ; k2f[l]=k[l]@Wq ; sv[l]=bq.k[l] ----
__global__ __launch_bounds__(256) void kk2(const float* __restrict__ f_w,
    const float* __restrict__ Wk, const float* __restrict__ bk,
    const float* __restrict__ Wq, const float* __restrict__ bq,
    float* __restrict__ k2f, float* __restrict__ sv) {
  int l = blockIdx.x;              // 240
  int t = threadIdx.x, wave = t >> 6, lane = t & 63;
  __shared__ float part[4][16][65];
  __shared__ float kl[D_];
  __shared__ float wsum[4];

  float4 x4 = ((const float4*)(f_w + (size_t)l * D_))[lane];

  for (int g = 0; g < 4; ++g) {
    int dbase = wave * 64 + g * 16;
#pragma unroll
    for (int i = 0; i < 16; ++i) {
      float4 w4 = ((const float4*)(Wk + (size_t)(dbase + i) * D_))[lane];
      part[wave][i][lane] = w4.x*x4.x + w4.y*x4.y + w4.z*x4.z + w4.w*x4.w;
    }
    float s = 0.f;
#pragma unroll
    for (int j = 0; j < 16; ++j)
      s += part[wave][lane & 15][(lane >> 4) * 16 + j];
    s += __shfl_xor(s, 16);
    s += __shfl_xor(s, 32);
    if (lane < 16) kl[dbase + lane] = s + bk[dbase + lane];
  }
  __syncthreads();

  float a0 = 0.f, a1 = 0.f, a2 = 0.f, a3 = 0.f;
#pragma unroll 4
  for (int d4 = 0; d4 < 64; ++d4) {
    float4 kv = ((const float4*)kl)[d4];
    a0 += kv.x * Wq[(size_t)(4*d4+0) * D_ + t];
    a1 += kv.y * Wq[(size_t)(4*d4+1) * D_ + t];
    a2 += kv.z * Wq[(size_t)(4*d4+2) * D_ + t];
    a3 += kv.w * Wq[(size_t)(4*d4+3) * D_ + t];
  }
  k2f[(size_t)l * D_ + t] = (a0 + a1) + (a2 + a3);

  float p = bq[t] * kl[t];
#pragma unroll
  for (int off = 32; off >= 1; off >>= 1) p += __shfl_xor(p, off);
  if (lane == 0) wsum[wave] = p;
  __syncthreads();
  if (t == 0) sv[l] = wsum[0] + wsum[1] + wsum[2] + wsum[3];
}

// ---- K1 (R14-20-proven): 256 blocks x 4 n-rows: aw=(f_b.k2f+sv)*scale -> softmax -> f_bq ----
__global__ __launch_bounds__(256) void aw_fbq(const float* __restrict__ f_b,
    const float* __restrict__ f_w, const float* __restrict__ f_s,
    const float* __restrict__ qmask, const float* __restrict__ lmask,
    const float* __restrict__ k2f, const float* __restrict__ sv,
    float* __restrict__ fbq) {
  int blk = blockIdx.x;
  int b = blk >> 5, n0 = (blk & 31) * 4;
  int t = threadIdx.x;

  __shared__ float k2l[L_][260];
  __shared__ float fbl[4][260];
  __shared__ float pdot[120][2];
  __shared__ float awl[4][32];
  __shared__ float slds[32];

  for (int r = 0; r < 4; ++r)
    fbl[r][t] = f_b[(size_t)(b * N_ + n0 + r) * D_ + t];
  for (int l = 0; l < L_; ++l)
    k2l[l][t] = k2f[(size_t)(b * L_ + l) * D_ + t];
  if (t < L_) slds[t] = sv[b * L_ + t];
  __syncthreads();

  if (t < 240) {
    int p = t % 120, half = t / 120;
    int r = p / 30, l = p % 30;
    const float4* fr = (const float4*)(fbl[r] + half * 128);
    const float4* kr = (const float4*)(k2l[l] + half * 128);
    float ac[4] = {0.f, 0.f, 0.f, 0.f};
#pragma unroll
    for (int j = 0; j < 32; ++j) {
      float4 fv = fr[j], kv = kr[j];
      ac[j & 3] += fv.x*kv.x + fv.y*kv.y + fv.z*kv.z + fv.w*kv.w;
    }
    pdot[p][half] = (ac[0] + ac[1]) + (ac[2] + ac[3]);
  }
  __syncthreads();

  if (t < 120) {
    int r = t / 30, l = t % 30;
    float acc = pdot[t][0] + pdot[t][1];
    float aw = (acc + slds[l]) * SCALE;
    float qm = qmask[b * L_ + l];
    awl[r][l] = (qm == 0.f) ? NEGV : aw * qm;
  }
  __syncthreads();

  if (t < 4) {
    float mx = -1e30f;
    for (int l = 0; l < L_; ++l) mx = fmaxf(mx, awl[t][l]);
    float s = 0.f;
    for (int l = 0; l < L_; ++l) { float e = __expf(awl[t][l] - mx); awl[t][l] = e; s += e; }
    float inv = 1.f / s;
    for (int l = 0; l < L_; ++l) awl[t][l] *= inv;
  }
  __syncthreads();

  for (int l = 0; l < L_; ++l)
    k2l[l][t] = f_w[(size_t)(b * L_ + l) * D_ + t];
  __syncthreads();

  float fsd = f_s[b * D_ + t];
  for (int r = 0; r < 4; ++r) {
    float f0 = 0.f, f1 = 0.f;
#pragma unroll
    for (int l = 0; l < L_; l += 2) {
      f0 += awl[r][l] * k2l[l][t];
      f1 += awl[r][l + 1] * k2l[l + 1][t];
    }
    float lm = lmask[b * N_ + n0 + r];
    fbq[(size_t)(b * N_ + n0 + r) * D_ + t] = fbl[r][t] * ((f0 + f1) * lm + fsd);
  }
}

// ---- K2 (R20 + DMA-staged phase C): fbq-first -> softmax -> fbb -> global_load_lds stream ----
// out[n,:] = f_b[n] + lmn*fbb + sum_m A'[n,m]*sigmoid(fm*fs)*fm
__global__ __launch_bounds__(256) void fused_stream(const float* __restrict__ f_b,
    const float* __restrict__ f_m, const float* __restrict__ f_s,
    const float* __restrict__ lmask, const float* __restrict__ fbq,
    float* __restrict__ out) {
  int bn = blockIdx.x, b = bn >> 7, n = bn & 127;
  int t = threadIdx.x, w = t >> 6, lane = t & 63;

  // part (phase A) aliases the DMA staging area (phase C): 8320 floats = 33.28 KB
  __shared__ __align__(16) float smem[4 * 32 * 65];
  __shared__ float a_lds[N_];
  __shared__ float sm[8];
  __shared__ float4 red[3][64];       // 3 KB
  __shared__ float fbbred[D_];        // 1 KB

  float (*part)[32][65] = (float (*)[32][65])smem;

  const float4* fbb = (const float4*)(f_b + (size_t)b * N_ * D_);
  int m0 = w * 32;

  // ---- Phase A fbq loads + dots FIRST (oldest in VM queue -> wait on L2 only)
  float4 qv = ((const float4*)(fbq + (size_t)bn * D_))[lane];
#pragma unroll 8
  for (int i = 0; i < 32; ++i) {
    float4 v = ((const float4*)(fbq + (size_t)(b * N_ + m0 + i) * D_))[lane];
    part[w][i][lane] = v.x*qv.x + v.y*qv.y + v.z*qv.z + v.w*qv.w;
  }
  __builtin_amdgcn_sched_barrier(0);

  __syncthreads();
  float s = 0.f;
#pragma unroll
  for (int j = 0; j < 32; ++j)
    s += part[w][lane & 31][(lane >> 5) * 32 + j];
  s += __shfl_xor(s, 32);
  if (lane < 32) a_lds[m0 + (lane & 31)] = s;
  __syncthreads();

  // softmax over 128, masked, * lmask[n]
  float lmn = lmask[b * N_ + n];
  float e = 0.f;
  if (t < N_) {
    float lm = lmask[b * N_ + t];
    float v = (lm == 0.f) ? NEGV : a_lds[t] * SCALE * lm;
    float mx = v;
#pragma unroll
    for (int off = 32; off >= 1; off >>= 1) mx = fmaxf(mx, __shfl_xor(mx, off));
    if (lane == 0) sm[w] = mx;
  }
  __syncthreads();
  if (t < N_) {
    float lm = lmask[b * N_ + t];
    float v = (lm == 0.f) ? NEGV : a_lds[t] * SCALE * lm;
    float gmax = fmaxf(sm[0], sm[1]);
    e = __expf(v - gmax);
    float ss = e;
#pragma unroll
    for (int off = 32; off >= 1; off >>= 1) ss += __shfl_xor(ss, off);
    if (lane == 0) sm[4 + w] = ss;
  }
  __syncthreads();
  if (t < N_) {
    float tot = sm[4] + sm[5];
    a_lds[t] = e * (lmn / tot);
  }
  __syncthreads();

  // Phase B: fbb[d] = sum_m a[m]*f_b[b,m,d] (coalesced, L2-hot; covered by later stream)
  {
    const float* fbcol = f_b + (size_t)b * N_ * D_ + t;
    float f0 = 0.f, f1 = 0.f;
#pragma unroll 8
    for (int m = 0; m < N_; m += 2) {
      f0 += a_lds[m]     * fbcol[(size_t)m * D_];
      f1 += a_lds[m + 1] * fbcol[(size_t)(m + 1) * D_];
    }
    fbbred[t] = f0 + f1;
  }
  __syncthreads();   // all part[] reads complete before DMA overwrites smem

  // ---- Phase C: f_m stream via global_load_lds DMA, wave-private double buffer
  // wave w stages rows m0+c*4..+3 into smem + w*2048 + (c&1)*1024, 1KB/row.
  float4 fs4 = ((const float4*)(f_s + (size_t)b * D_))[lane];
  const float CLOG = -1.44269504088896f;  // -log2(e)
  float4 cs;
  cs.x = fs4.x * CLOG; cs.y = fs4.y * CLOG;
  cs.z = fs4.z * CLOG; cs.w = fs4.w * CLOG;
  float4 acc = make_float4(0.f, 0.f, 0.f, 0.f);

  float* mystage = smem + w * 2048;
  const float* fmbase = f_m + (size_t)bn * N_ * D_;

  // drain any stale VMEM so vmcnt counting below is exact
  asm volatile("s_waitcnt vmcnt(0)" ::: "memory");
  __builtin_amdgcn_sched_barrier(0);

  auto issue_chunk = [&](int c) {
#pragma unroll
    for (int r = 0; r < 4; ++r) {
      const float* g = fmbase + (size_t)(m0 + c * 4 + r) * D_ + lane * 4;
      float* lp = mystage + (c & 1) * 1024 + r * 256;
      __builtin_amdgcn_global_load_lds((as1_cvptr)(const void*)g,
                                       (as3_vptr)(void*)lp, 16, 0, 0);
    }
  };

  issue_chunk(0);
  issue_chunk(1);

#pragma unroll
  for (int c = 0; c < 8; ++c) {
    if (c < 7) { asm volatile("s_waitcnt vmcnt(4)" ::: "memory"); }
    else       { asm volatile("s_waitcnt vmcnt(0)" ::: "memory"); }
    __builtin_amdgcn_sched_barrier(0);
    const float* buf = mystage + (c & 1) * 1024;
    float4 v[4];
#pragma unroll
    for (int r = 0; r < 4; ++r)
      v[r] = *(const float4*)(buf + r * 256 + lane * 4);
    __builtin_amdgcn_sched_barrier(0);
    if (c + 2 < 8) issue_chunk(c + 2);
#pragma unroll
    for (int r = 0; r < 4; ++r) {
      float a = a_lds[m0 + c * 4 + r];
      float4 fm4 = v[r];
      float gx = __builtin_amdgcn_rcpf(1.f + __builtin_amdgcn_exp2f(fm4.x * cs.x));
      float gy = __builtin_amdgcn_rcpf(1.f + __builtin_amdgcn_exp2f(fm4.y * cs.y));
      float gz = __builtin_amdgcn_rcpf(1.f + __builtin_amdgcn_exp2f(fm4.z * cs.z));
      float gw = __builtin_amdgcn_rcpf(1.f + __builtin_amdgcn_exp2f(fm4.w * cs.w));
      acc.x += a * (gx * fm4.x);
      acc.y += a * (gy * fm4.y);
      acc.z += a * (gz * fm4.z);
      acc.w += a * (gw * fm4.w);
    }
  }

  // epilogue
  if (w > 0) red[w - 1][lane] = acc;
  __syncthreads();
  if (w == 0) {
#pragma unroll
    for (int j = 0; j < 3; ++j) {
      float4 r4 = red[j][lane];
      acc.x += r4.x; acc.y += r4.y; acc.z += r4.z; acc.w += r4.w;
    }
    float4 fbn = fbb[(size_t)n * 64 + lane];
    float4 bb = ((const float4*)fbbred)[lane];
    float4 o;
    o.x = fbn.x + acc.x + lmn * bb.x;
    o.y = fbn.y + acc.y + lmn * bb.y;
    o.z = fbn.z + acc.z + lmn * bb.z;
    o.w = fbn.w + acc.w + lmn * bb.w;
    ((float4*)out)[(size_t)bn * 64 + lane] = o;
  }
}

extern "C" void kernel_launch(void* const* d_in, const int* in_sizes, int n_in,
                              void* d_out, int out_size, void* d_ws, size_t ws_size,
                              hipStream_t stream) {
  const float* f_b   = (const float*)d_in[0];
  const float* f_w   = (const float*)d_in[1];
  const float* f_s   = (const float*)d_in[2];
  const float* f_m   = (const float*)d_in[3];
  const float* qmask = (const float*)d_in[4];
  const float* lmask = (const float*)d_in[5];
  const float* Wq    = (const float*)d_in[6];
  const float* bq    = (const float*)d_in[7];
  const float* Wk    = (const float*)d_in[8];
  const float* bk    = (const float*)d_in[9];
  float* out = (float*)d_out;

  float* ws  = (float*)d_ws;
  float* k2f = ws;                          // 61440 (pad 65536)
  float* sv  = ws + 65536;                  // 240  (pad 1024)
  float* fbq = ws + 131072;                 // 262144

  hipLaunchKernelGGL(kk2, dim3(B_ * L_), dim3(256), 0, stream,
                     f_w, Wk, bk, Wq, bq, k2f, sv);
  hipLaunchKernelGGL(aw_fbq, dim3(256), dim3(256), 0, stream,
                     f_b, f_w, f_s, qmask, lmask, k2f, sv, fbq);
  hipLaunchKernelGGL(fused_stream, dim3(B_ * N_), dim3(256), 0, stream,
                     f_b, f_m, f_s, lmask, fbq, out);
}

// Round 23
// 52.664 us; speedup vs baseline: 1.7939x; 1.0640x over previous
//
#include <hip/hip_runtime.h>
#include <math.h>

#define B_ 8
#define N_ 128
#define L_ 30
#define D_ 256
#define NEGV -1000000000.0f
#define SCALE 0.0625f   // 1/sqrt(256)

// ---- K0 (R15-20-proven): 240 blocks, block l: k[l]=f_w[l]@Wk^T+bk ; k2f[l]=k[l]@Wq ; sv[l]=bq.k[l] ----
__global__ __launch_bounds__(256) void kk2(const float* __restrict__ f_w,
    const float* __restrict__ Wk, const float* __restrict__ bk,
    const float* __restrict__ Wq, const float* __restrict__ bq,
    float* __restrict__ k2f, float* __restrict__ sv) {
  int l = blockIdx.x;              // 240
  int t = threadIdx.x, wave = t >> 6, lane = t & 63;
  __shared__ float part[4][16][65];
  __shared__ float kl[D_];
  __shared__ float wsum[4];

  float4 x4 = ((const float4*)(f_w + (size_t)l * D_))[lane];

  for (int g = 0; g < 4; ++g) {
    int dbase = wave * 64 + g * 16;
#pragma unroll
    for (int i = 0; i < 16; ++i) {
      float4 w4 = ((const float4*)(Wk + (size_t)(dbase + i) * D_))[lane];
      part[wave][i][lane] = w4.x*x4.x + w4.y*x4.y + w4.z*x4.z + w4.w*x4.w;
    }
    float s = 0.f;
#pragma unroll
    for (int j = 0; j < 16; ++j)
      s += part[wave][lane & 15][(lane >> 4) * 16 + j];
    s += __shfl_xor(s, 16);
    s += __shfl_xor(s, 32);
    if (lane < 16) kl[dbase + lane] = s + bk[dbase + lane];
  }
  __syncthreads();

  float a0 = 0.f, a1 = 0.f, a2 = 0.f, a3 = 0.f;
#pragma unroll 4
  for (int d4 = 0; d4 < 64; ++d4) {
    float4 kv = ((const float4*)kl)[d4];
    a0 += kv.x * Wq[(size_t)(4*d4+0) * D_ + t];
    a1 += kv.y * Wq[(size_t)(4*d4+1) * D_ + t];
    a2 += kv.z * Wq[(size_t)(4*d4+2) * D_ + t];
    a3 += kv.w * Wq[(size_t)(4*d4+3) * D_ + t];
  }
  k2f[(size_t)l * D_ + t] = (a0 + a1) + (a2 + a3);

  float p = bq[t] * kl[t];
#pragma unroll
  for (int off = 32; off >= 1; off >>= 1) p += __shfl_xor(p, off);
  if (lane == 0) wsum[wave] = p;
  __syncthreads();
  if (t == 0) sv[l] = wsum[0] + wsum[1] + wsum[2] + wsum[3];
}

// ---- K1 (R14-20-proven): 256 blocks x 4 n-rows: aw=(f_b.k2f+sv)*scale -> softmax -> f_bq ----
__global__ __launch_bounds__(256) void aw_fbq(const float* __restrict__ f_b,
    const float* __restrict__ f_w, const float* __restrict__ f_s,
    const float* __restrict__ qmask, const float* __restrict__ lmask,
    const float* __restrict__ k2f, const float* __restrict__ sv,
    float* __restrict__ fbq) {
  int blk = blockIdx.x;
  int b = blk >> 5, n0 = (blk & 31) * 4;
  int t = threadIdx.x;

  __shared__ float k2l[L_][260];
  __shared__ float fbl[4][260];
  __shared__ float pdot[120][2];
  __shared__ float awl[4][32];
  __shared__ float slds[32];

  for (int r = 0; r < 4; ++r)
    fbl[r][t] = f_b[(size_t)(b * N_ + n0 + r) * D_ + t];
  for (int l = 0; l < L_; ++l)
    k2l[l][t] = k2f[(size_t)(b * L_ + l) * D_ + t];
  if (t < L_) slds[t] = sv[b * L_ + t];
  __syncthreads();

  if (t < 240) {
    int p = t % 120, half = t / 120;
    int r = p / 30, l = p % 30;
    const float4* fr = (const float4*)(fbl[r] + half * 128);
    const float4* kr = (const float4*)(k2l[l] + half * 128);
    float ac[4] = {0.f, 0.f, 0.f, 0.f};
#pragma unroll
    for (int j = 0; j < 32; ++j) {
      float4 fv = fr[j], kv = kr[j];
      ac[j & 3] += fv.x*kv.x + fv.y*kv.y + fv.z*kv.z + fv.w*kv.w;
    }
    pdot[p][half] = (ac[0] + ac[1]) + (ac[2] + ac[3]);
  }
  __syncthreads();

  if (t < 120) {
    int r = t / 30, l = t % 30;
    float acc = pdot[t][0] + pdot[t][1];
    float aw = (acc + slds[l]) * SCALE;
    float qm = qmask[b * L_ + l];
    awl[r][l] = (qm == 0.f) ? NEGV : aw * qm;
  }
  __syncthreads();

  if (t < 4) {
    float mx = -1e30f;
    for (int l = 0; l < L_; ++l) mx = fmaxf(mx, awl[t][l]);
    float s = 0.f;
    for (int l = 0; l < L_; ++l) { float e = __expf(awl[t][l] - mx); awl[t][l] = e; s += e; }
    float inv = 1.f / s;
    for (int l = 0; l < L_; ++l) awl[t][l] *= inv;
  }
  __syncthreads();

  for (int l = 0; l < L_; ++l)
    k2l[l][t] = f_w[(size_t)(b * L_ + l) * D_ + t];
  __syncthreads();

  float fsd = f_s[b * D_ + t];
  for (int r = 0; r < 4; ++r) {
    float f0 = 0.f, f1 = 0.f;
#pragma unroll
    for (int l = 0; l < L_; l += 2) {
      f0 += awl[r][l] * k2l[l][t];
      f1 += awl[r][l + 1] * k2l[l + 1][t];
    }
    float lm = lmask[b * N_ + n0 + r];
    fbq[(size_t)(b * N_ + n0 + r) * D_ + t] = fbl[r][t] * ((f0 + f1) * lm + fsd);
  }
}

// ---- K2 (R20-proven, byte-identical): fbq-first -> deep f_m preload -> softmax -> fbb -> stream ----
__global__ __launch_bounds__(256) void fused_stream(const float* __restrict__ f_b,
    const float* __restrict__ f_m, const float* __restrict__ f_s,
    const float* __restrict__ lmask, const float* __restrict__ fbq,
    float* __restrict__ out) {
  int bn = blockIdx.x, b = bn >> 7, n = bn & 127;
  int t = threadIdx.x, w = t >> 6, lane = t & 63;

  __shared__ float part[4][32][65];   // 33.3 KB
  __shared__ float a_lds[N_];
  __shared__ float sm[8];
  __shared__ float4 red[3][64];       // 3 KB
  __shared__ float fbbred[D_];        // 1 KB

  const float4* fmb = (const float4*)(f_m + (size_t)bn * N_ * D_);
  const float4* fbb = (const float4*)(f_b + (size_t)b * N_ * D_);
  int m0 = w * 32;

  // ---- Phase A fbq loads + dots FIRST (oldest in VM queue -> dots wait on L2 only)
  float4 qv = ((const float4*)(fbq + (size_t)bn * D_))[lane];
#pragma unroll 8
  for (int i = 0; i < 32; ++i) {
    float4 v = ((const float4*)(fbq + (size_t)(b * N_ + m0 + i) * D_))[lane];
    part[w][i][lane] = v.x*qv.x + v.y*qv.y + v.z*qv.z + v.w*qv.w;
  }
  __builtin_amdgcn_sched_barrier(0);

  // ---- f_m deep preload (issued after fbq loads; in flight through softmax+fbb)
  float4 pA[8], pB[8];
#pragma unroll
  for (int i = 0; i < 8; ++i) pA[i] = fmb[(size_t)(m0 + i) * 64 + lane];
#pragma unroll
  for (int i = 0; i < 8; ++i) pB[i] = fmb[(size_t)(m0 + 8 + i) * 64 + lane];
  __builtin_amdgcn_sched_barrier(0);

  __syncthreads();
  float s = 0.f;
#pragma unroll
  for (int j = 0; j < 32; ++j)
    s += part[w][lane & 31][(lane >> 5) * 32 + j];
  s += __shfl_xor(s, 32);
  if (lane < 32) a_lds[m0 + (lane & 31)] = s;
  __syncthreads();

  // softmax over 128, masked, * lmask[n]
  float lmn = lmask[b * N_ + n];
  float e = 0.f;
  if (t < N_) {
    float lm = lmask[b * N_ + t];
    float v = (lm == 0.f) ? NEGV : a_lds[t] * SCALE * lm;
    float mx = v;
#pragma unroll
    for (int off = 32; off >= 1; off >>= 1) mx = fmaxf(mx, __shfl_xor(mx, off));
    if (lane == 0) sm[w] = mx;
  }
  __syncthreads();
  if (t < N_) {
    float lm = lmask[b * N_ + t];
    float v = (lm == 0.f) ? NEGV : a_lds[t] * SCALE * lm;
    float gmax = fmaxf(sm[0], sm[1]);
    e = __expf(v - gmax);
    float ss = e;
#pragma unroll
    for (int off = 32; off >= 1; off >>= 1) ss += __shfl_xor(ss, off);
    if (lane == 0) sm[4 + w] = ss;
  }
  __syncthreads();
  if (t < N_) {
    float tot = sm[4] + sm[5];
    a_lds[t] = e * (lmn / tot);
  }
  __syncthreads();

  // Phase B: fbb[d] = sum_m a[m]*f_b[b,m,d] — covered by stream below
  {
    const float* fbcol = f_b + (size_t)b * N_ * D_ + t;
    float f0 = 0.f, f1 = 0.f;
#pragma unroll 8
    for (int m = 0; m < N_; m += 2) {
      f0 += a_lds[m]     * fbcol[(size_t)m * D_];
      f1 += a_lds[m + 1] * fbcol[(size_t)(m + 1) * D_];
    }
    fbbred[t] = f0 + f1;
  }

  // Phase C: pure sigmoid f_m stream, double-buffered
  float4 fs4 = ((const float4*)(f_s + (size_t)b * D_))[lane];
  const float CLOG = -1.44269504088896f;  // -log2(e)
  float4 cs;
  cs.x = fs4.x * CLOG; cs.y = fs4.y * CLOG;
  cs.z = fs4.z * CLOG; cs.w = fs4.w * CLOG;
  float4 acc = make_float4(0.f, 0.f, 0.f, 0.f);

  auto compute8 = [&](float4 (&P)[8], int mbase) {
#pragma unroll
    for (int i = 0; i < 8; ++i) {
      float a = a_lds[mbase + i];
      float4 fm4 = P[i];
      float gx = __builtin_amdgcn_rcpf(1.f + __builtin_amdgcn_exp2f(fm4.x * cs.x));
      float gy = __builtin_amdgcn_rcpf(1.f + __builtin_amdgcn_exp2f(fm4.y * cs.y));
      float gz = __builtin_amdgcn_rcpf(1.f + __builtin_amdgcn_exp2f(fm4.z * cs.z));
      float gw = __builtin_amdgcn_rcpf(1.f + __builtin_amdgcn_exp2f(fm4.w * cs.w));
      acc.x += a * (gx * fm4.x);
      acc.y += a * (gy * fm4.y);
      acc.z += a * (gz * fm4.z);
      acc.w += a * (gw * fm4.w);
    }
  };

  compute8(pA, m0);
#pragma unroll
  for (int i = 0; i < 8; ++i) pA[i] = fmb[(size_t)(m0 + 16 + i) * 64 + lane];
  compute8(pB, m0 + 8);
#pragma unroll
  for (int i = 0; i < 8; ++i) pB[i] = fmb[(size_t)(m0 + 24 + i) * 64 + lane];
  compute8(pA, m0 + 16);
  compute8(pB, m0 + 24);

  // epilogue
  if (w > 0) red[w - 1][lane] = acc;
  __syncthreads();
  if (w == 0) {
#pragma unroll
    for (int j = 0; j < 3; ++j) {
      float4 r4 = red[j][lane];
      acc.x += r4.x; acc.y += r4.y; acc.z += r4.z; acc.w += r4.w;
    }
    float4 fbn = fbb[(size_t)n * 64 + lane];
    float4 bb = ((const float4*)fbbred)[lane];
    float4 o;
    o.x = fbn.x + acc.x + lmn * bb.x;
    o.y = fbn.y + acc.y + lmn * bb.y;
    o.z = fbn.z + acc.z + lmn * bb.z;
    o.w = fbn.w + acc.w + lmn * bb.w;
    ((float4*)out)[(size_t)bn * 64 + lane] = o;
  }
}

extern "C" void kernel_launch(void* const* d_in, const int* in_sizes, int n_in,
                              void* d_out, int out_size, void* d_ws, size_t ws_size,
                              hipStream_t stream) {
  const float* f_b   = (const float*)d_in[0];
  const float* f_w   = (const float*)d_in[1];
  const float* f_s   = (const float*)d_in[2];
  const float* f_m   = (const float*)d_in[3];
  const float* qmask = (const float*)d_in[4];
  const float* lmask = (const float*)d_in[5];
  const float* Wq    = (const float*)d_in[6];
  const float* bq    = (const float*)d_in[7];
  const float* Wk    = (const float*)d_in[8];
  const float* bk    = (const float*)d_in[9];
  float* out = (float*)d_out;

  float* ws  = (float*)d_ws;
  float* k2f = ws;                          // 61440 (pad 65536)
  float* sv  = ws + 65536;                  // 240  (pad 1024)
  float* fbq = ws + 131072;                 // 262144

  hipLaunchKernelGGL(kk2, dim3(B_ * L_), dim3(256), 0, stream,
                     f_w, Wk, bk, Wq, bq, k2f, sv);
  hipLaunchKernelGGL(aw_fbq, dim3(256), dim3(256), 0, stream,
                     f_b, f_w, f_s, qmask, lmask, k2f, sv, fbq);
  hipLaunchKernelGGL(fused_stream, dim3(B_ * N_), dim3(256), 0, stream,
                     f_b, f_m, f_s, lmask, fbq, out);
}